// Round 2
// baseline (1644.707 us; speedup 1.0000x reference)
//
#include <hip/hip_runtime.h>
#include <hip/hip_bf16.h>
#include <cstdint>

// ---------- types ----------
typedef __bf16 bf16x8 __attribute__((ext_vector_type(8)));
typedef float f32x4 __attribute__((ext_vector_type(4)));
typedef unsigned short u16;
typedef unsigned short u16x8 __attribute__((ext_vector_type(8)));
typedef unsigned short u16x4 __attribute__((ext_vector_type(4)));

#define EMBED 1024
#define HIDDEN 512
#define SEQ 4096
#define NBATCH 4
#define MTOT (NBATCH * SEQ)  // 16384

__device__ __forceinline__ u16 f32_to_bf16(float f) {
  union { float f; uint32_t u; } v; v.f = f;
  uint32_t r = v.u + 0x7fffu + ((v.u >> 16) & 1u);
  return (u16)(r >> 16);
}

// ---------- elementwise f32 -> bf16 ----------
__global__ __launch_bounds__(256) void cvt_bf16_kernel(const float* __restrict__ src,
                                                       u16* __restrict__ dst) {
  int i = blockIdx.x * 256 + threadIdx.x;
  float4 v = ((const float4*)src)[i];
  u16x4 o;
  o[0] = f32_to_bf16(v.x); o[1] = f32_to_bf16(v.y);
  o[2] = f32_to_bf16(v.z); o[3] = f32_to_bf16(v.w);
  ((u16x4*)dst)[i] = o;
}

// ---------- weight transpose+convert: src[K][N] f32 -> dst[N][K] bf16 ----------
__global__ __launch_bounds__(256) void transpose_w_kernel(const float* __restrict__ src,
                                                          u16* __restrict__ dst,
                                                          int log2N, int K) {
  int idx = blockIdx.x * 256 + threadIdx.x;
  int N = 1 << log2N;
  int k = idx >> log2N;
  int n = idx & (N - 1);
  dst[(size_t)n * K + k] = f32_to_bf16(src[idx]);
}

// ---------- GEMM: C[M,N] = A[M,K] * Bt[N,K]^T  (bf16 in, fp32 acc) ----------
// MODE 0: bf16 out, every element scaled by `scale` (Q pre-scale / 1.0)
// MODE 1: bf16 out, + bias[col] + resid[row*ldc+col] (fp32 residual)
// MODE 2: fp32 out
template <int MODE>
__global__ __launch_bounds__(256, 3) void gemm_bt_kernel(
    const u16* __restrict__ A, const u16* __restrict__ Bt, void* __restrict__ Cout,
    const float* __restrict__ bias, const float* __restrict__ resid,
    int ldc, int K, float scale) {
  __shared__ u16 As[128][40];  // stride 40 u16 = 80B: 16B-aligned rows, 2-way-bank only
  __shared__ u16 Bs[128][40];
  const int tid = threadIdx.x;
  const int lane = tid & 63;
  const int wave = tid >> 6;
  const int quad = lane >> 4;
  const int l15 = lane & 15;
  const int m0 = blockIdx.x * 128;
  const int n0 = blockIdx.y * 128;
  const int wm = (wave & 1) * 64;
  const int wn = (wave >> 1) * 64;

  f32x4 acc[4][4];
#pragma unroll
  for (int i = 0; i < 4; ++i)
#pragma unroll
    for (int j = 0; j < 4; ++j) {
      acc[i][j][0] = 0.f; acc[i][j][1] = 0.f; acc[i][j][2] = 0.f; acc[i][j][3] = 0.f;
    }

  for (int k0 = 0; k0 < K; k0 += 32) {
    __syncthreads();
#pragma unroll
    for (int p = 0; p < 2; ++p) {
      int c = tid + p * 256;        // 512 chunks of 8 elems: 128 rows x 4 chunks
      int r = c >> 2;
      int c8 = (c & 3) * 8;
      *(u16x8*)&As[r][c8] = *(const u16x8*)&A[(size_t)(m0 + r) * K + k0 + c8];
      *(u16x8*)&Bs[r][c8] = *(const u16x8*)&Bt[(size_t)(n0 + r) * K + k0 + c8];
    }
    __syncthreads();
    bf16x8 af[4], bfr[4];
#pragma unroll
    for (int i = 0; i < 4; ++i) af[i] = *(const bf16x8*)&As[wm + i * 16 + l15][quad * 8];
#pragma unroll
    for (int j = 0; j < 4; ++j) bfr[j] = *(const bf16x8*)&Bs[wn + j * 16 + l15][quad * 8];
#pragma unroll
    for (int i = 0; i < 4; ++i)
#pragma unroll
      for (int j = 0; j < 4; ++j)
        acc[i][j] = __builtin_amdgcn_mfma_f32_16x16x32_bf16(af[i], bfr[j], acc[i][j], 0, 0, 0);
  }

  // epilogue: C/D layout col=lane&15, row=quad*4+reg  [guide m89/m91]
#pragma unroll
  for (int i = 0; i < 4; ++i) {
    const int row = m0 + wm + i * 16 + quad * 4;
#pragma unroll
    for (int j = 0; j < 4; ++j) {
      const int col = n0 + wn + j * 16 + l15;
#pragma unroll
      for (int r = 0; r < 4; ++r) {
        float v = acc[i][j][r];
        const size_t off = (size_t)(row + r) * ldc + col;
        if (MODE == 0) {
          ((u16*)Cout)[off] = f32_to_bf16(v * scale);
        } else if (MODE == 1) {
          v += bias[col] + resid[off];
          ((u16*)Cout)[off] = f32_to_bf16(v);
        } else {
          ((float*)Cout)[off] = v;
        }
      }
    }
  }
}

// ---------- flash attention ----------
// QKV: [16384, 1536] bf16 rows (Q|K|V), Q pre-scaled by 1/sqrt(512).
// grid (SEQ/64, NBATCH); block 256 = 4 waves; wave handles 16 q-rows, full D=512.
__global__ __launch_bounds__(256, 2) void flash_kernel(const u16* __restrict__ QKV,
                                                       u16* __restrict__ ctx) {
  __shared__ u16 Ks[32][520];      // K tile [kv][d], pad 512+8
  __shared__ u16 Vs[512][40];      // V tile transposed [d][kv], pad 32+8
  __shared__ u16 Ps[4][16][40];    // per-wave P round-trip [qrow][kv]
  const int tid = threadIdx.x;
  const int lane = tid & 63;
  const int wave = tid >> 6;
  const int quad = lane >> 4;
  const int l15 = lane & 15;
  const int base = blockIdx.y * SEQ;
  const int q0 = blockIdx.x * 64;

  // Q fragments resident in registers: A-layout m=lane&15, k=quad*8+j  [guide m120]
  bf16x8 qf[16];
  {
    const u16* qp = QKV + (size_t)(base + q0 + wave * 16 + l15) * 1536 + quad * 8;
#pragma unroll
    for (int ks = 0; ks < 16; ++ks) qf[ks] = *(const bf16x8*)(qp + ks * 32);
  }

  f32x4 O[32];
#pragma unroll
  for (int i = 0; i < 32; ++i) { O[i][0] = 0.f; O[i][1] = 0.f; O[i][2] = 0.f; O[i][3] = 0.f; }
  float m_run[4] = {-INFINITY, -INFINITY, -INFINITY, -INFINITY};
  float l_run[4] = {0.f, 0.f, 0.f, 0.f};

  for (int kv0 = 0; kv0 < SEQ; kv0 += 32) {
    __syncthreads();
    // stage K tile + V tile (transposed): 32 rows x 512 cols each
#pragma unroll
    for (int p = 0; p < 8; ++p) {
      int c = tid + p * 256;
      int r = c >> 6;
      int c8 = (c & 63) * 8;
      const size_t grow = (size_t)(base + kv0 + r) * 1536;
      *(u16x8*)&Ks[r][c8] = *(const u16x8*)&QKV[grow + HIDDEN + c8];
      u16x8 vv = *(const u16x8*)&QKV[grow + 2 * HIDDEN + c8];
#pragma unroll
      for (int j = 0; j < 8; ++j) Vs[c8 + j][r] = vv[j];
    }
    __syncthreads();

    // S tile: 16 q-rows x 32 kv-cols (two 16x16 MFMA col-tiles)
    f32x4 s0, s1;
    s0[0] = 0.f; s0[1] = 0.f; s0[2] = 0.f; s0[3] = 0.f;
    s1[0] = 0.f; s1[1] = 0.f; s1[2] = 0.f; s1[3] = 0.f;
#pragma unroll
    for (int ks = 0; ks < 16; ++ks) {
      bf16x8 b0 = *(const bf16x8*)&Ks[l15][ks * 32 + quad * 8];
      bf16x8 b1 = *(const bf16x8*)&Ks[16 + l15][ks * 32 + quad * 8];
      s0 = __builtin_amdgcn_mfma_f32_16x16x32_bf16(qf[ks], b0, s0, 0, 0, 0);
      s1 = __builtin_amdgcn_mfma_f32_16x16x32_bf16(qf[ks], b1, s1, 0, 0, 0);
    }

    // online softmax; row = quad*4+reg lives in the 16 lanes of this quad
    float tmax[4], alpha[4], p0[4], p1[4], tsum[4];
#pragma unroll
    for (int r = 0; r < 4; ++r) tmax[r] = fmaxf(s0[r], s1[r]);
#pragma unroll
    for (int m = 1; m <= 8; m <<= 1)
#pragma unroll
      for (int r = 0; r < 4; ++r) tmax[r] = fmaxf(tmax[r], __shfl_xor(tmax[r], m));
    bool aone = true;
#pragma unroll
    for (int r = 0; r < 4; ++r) {
      float mnew = fmaxf(m_run[r], tmax[r]);
      alpha[r] = __expf(m_run[r] - mnew);
      m_run[r] = mnew;
      p0[r] = __expf(s0[r] - mnew);
      p1[r] = __expf(s1[r] - mnew);
      tsum[r] = p0[r] + p1[r];
      aone = aone && (alpha[r] == 1.0f);
    }
#pragma unroll
    for (int m = 1; m <= 8; m <<= 1)
#pragma unroll
      for (int r = 0; r < 4; ++r) tsum[r] += __shfl_xor(tsum[r], m);
#pragma unroll
    for (int r = 0; r < 4; ++r) l_run[r] = l_run[r] * alpha[r] + tsum[r];
    if (!__all(aone)) {
#pragma unroll
      for (int i = 0; i < 32; ++i)
#pragma unroll
        for (int r = 0; r < 4; ++r) O[i][r] *= alpha[r];
    }

    // P: C-layout -> LDS -> A-layout
#pragma unroll
    for (int r = 0; r < 4; ++r) {
      Ps[wave][quad * 4 + r][l15] = f32_to_bf16(p0[r]);
      Ps[wave][quad * 4 + r][16 + l15] = f32_to_bf16(p1[r]);
    }
    __syncthreads();
    bf16x8 pf = *(const bf16x8*)&Ps[wave][l15][quad * 8];
#pragma unroll
    for (int nt = 0; nt < 32; ++nt) {
      bf16x8 vf = *(const bf16x8*)&Vs[nt * 16 + l15][quad * 8];
      O[nt] = __builtin_amdgcn_mfma_f32_16x16x32_bf16(pf, vf, O[nt], 0, 0, 0);
    }
  }

#pragma unroll
  for (int r = 0; r < 4; ++r) l_run[r] = 1.0f / l_run[r];
  const int orow = base + q0 + wave * 16 + quad * 4;
#pragma unroll
  for (int nt = 0; nt < 32; ++nt)
#pragma unroll
    for (int r = 0; r < 4; ++r)
      ctx[(size_t)(orow + r) * HIDDEN + nt * 16 + l15] = f32_to_bf16(O[nt][r] * l_run[r]);
}

// ---------- layernorm (in-place on d_out fp32, 1024 cols/row) ----------
__global__ __launch_bounds__(256) void ln_kernel(float* __restrict__ io,
                                                 const float* __restrict__ g,
                                                 const float* __restrict__ b) {
  const int row = blockIdx.x;
  const int tid = threadIdx.x;
  float* x = io + (size_t)row * EMBED;
  float4 v = *(const float4*)(x + tid * 4);
  float s1 = v.x + v.y + v.z + v.w;
  float s2 = v.x * v.x + v.y * v.y + v.z * v.z + v.w * v.w;
#pragma unroll
  for (int m = 1; m <= 32; m <<= 1) {
    s1 += __shfl_xor(s1, m);
    s2 += __shfl_xor(s2, m);
  }
  __shared__ float rs1[4], rs2[4];
  const int wave = tid >> 6;
  if ((tid & 63) == 0) { rs1[wave] = s1; rs2[wave] = s2; }
  __syncthreads();
  s1 = rs1[0] + rs1[1] + rs1[2] + rs1[3];
  s2 = rs2[0] + rs2[1] + rs2[2] + rs2[3];
  const float mu = s1 * (1.f / EMBED);
  const float var = s2 * (1.f / EMBED) - mu * mu;
  const float rinv = rsqrtf(var + 1e-5f);
  float4 gg = *(const float4*)(g + tid * 4);
  float4 bb = *(const float4*)(b + tid * 4);
  float4 o;
  o.x = (v.x - mu) * rinv * gg.x + bb.x;
  o.y = (v.y - mu) * rinv * gg.y + bb.y;
  o.z = (v.z - mu) * rinv * gg.z + bb.z;
  o.w = (v.w - mu) * rinv * gg.w + bb.w;
  *(float4*)(x + tid * 4) = o;
}

// ---------- launch ----------
extern "C" void kernel_launch(void* const* d_in, const int* in_sizes, int n_in,
                              void* d_out, int out_size, void* d_ws, size_t ws_size,
                              hipStream_t stream) {
  const float* q_feat = (const float*)d_in[0];
  const float* kv_feat = (const float*)d_in[1];
  const float* Wq = (const float*)d_in[2];
  const float* Wk = (const float*)d_in[3];
  const float* Wv = (const float*)d_in[4];
  const float* Wo = (const float*)d_in[5];
  const float* bo = (const float*)d_in[6];
  const float* Wfc = (const float*)d_in[7];
  const float* ln_g = (const float*)d_in[8];
  const float* ln_b = (const float*)d_in[9];
  float* out = (float*)d_out;

  // ws carve (total 140,509,184 B)
  char* ws = (char*)d_ws;
  u16* Aq    = (u16*)(ws + 0);           // 33,554,432  (later aliased as out1)
  u16* Akv   = (u16*)(ws + 33554432);    // 33,554,432
  u16* Wcat  = (u16*)(ws + 67108864);    //  3,145,728  [1536,1024] bf16 (Wq^T|Wk^T|Wv^T)
  u16* Wo_t  = (u16*)(ws + 70254592);    //  1,048,576  [1024,512]
  u16* Wfc_t = (u16*)(ws + 71303168);    //  2,097,152  [1024,1024]
  u16* QKV   = (u16*)(ws + 73400320);    // 50,331,648  [16384,1536]
  u16* ctx   = (u16*)(ws + 123731968);   // 16,777,216  [16384,512]
  u16* out1  = Aq;                       // alias: Aq dead after Q-projection

  const float qscale = 0.044194173824159216f;  // 1/sqrt(512)

  // 1. activations -> bf16
  cvt_bf16_kernel<<<MTOT * EMBED / 1024, 256, 0, stream>>>(q_feat, Aq);
  cvt_bf16_kernel<<<MTOT * EMBED / 1024, 256, 0, stream>>>(kv_feat, Akv);
  // 2. weights -> transposed bf16
  transpose_w_kernel<<<(EMBED * HIDDEN) / 256, 256, 0, stream>>>(Wq, Wcat, 9, EMBED);
  transpose_w_kernel<<<(EMBED * HIDDEN) / 256, 256, 0, stream>>>(Wk, Wcat + 512 * 1024, 9, EMBED);
  transpose_w_kernel<<<(EMBED * HIDDEN) / 256, 256, 0, stream>>>(Wv, Wcat + 1024 * 1024, 9, EMBED);
  transpose_w_kernel<<<(HIDDEN * EMBED) / 256, 256, 0, stream>>>(Wo, Wo_t, 10, HIDDEN);
  transpose_w_kernel<<<(EMBED * EMBED) / 256, 256, 0, stream>>>(Wfc, Wfc_t, 10, EMBED);
  // 3a. Q projection from q_feat (pre-scaled): QKV cols [0,512)
  gemm_bt_kernel<0><<<dim3(MTOT / 128, HIDDEN / 128), 256, 0, stream>>>(
      Aq, Wcat, QKV, nullptr, nullptr, 1536, EMBED, qscale);
  // 3b. K|V projection from kv_feat: QKV cols [512,1536)
  gemm_bt_kernel<0><<<dim3(MTOT / 128, 1024 / 128), 256, 0, stream>>>(
      Akv, Wcat + 512 * 1024, QKV + 512, nullptr, nullptr, 1536, EMBED, 1.0f);
  // 4. flash attention
  flash_kernel<<<dim3(SEQ / 64, NBATCH), 256, 0, stream>>>(QKV, ctx);
  // 5. out1 = ctx @ Wo^T + bo + q_feat  (bf16)
  gemm_bt_kernel<1><<<dim3(MTOT / 128, EMBED / 128), 256, 0, stream>>>(
      ctx, Wo_t, out1, bo, q_feat, EMBED, HIDDEN, 0.f);
  // 6. out2 = out1 @ Wfc^T (fp32 -> d_out)
  gemm_bt_kernel<2><<<dim3(MTOT / 128, EMBED / 128), 256, 0, stream>>>(
      out1, Wfc_t, out, nullptr, nullptr, EMBED, EMBED, 0.f);
  // 7. layernorm in-place
  ln_kernel<<<MTOT, 256, 0, stream>>>(out, ln_g, ln_b);

  (void)in_sizes; (void)n_in; (void)out_size; (void)ws_size;
}

// Round 3
// 776.115 us; speedup vs baseline: 2.1192x; 2.1192x over previous
//
#include <hip/hip_runtime.h>
#include <hip/hip_bf16.h>
#include <cstdint>

// ---------- types ----------
typedef __bf16 bf16x8 __attribute__((ext_vector_type(8)));
typedef float f32x4 __attribute__((ext_vector_type(4)));
typedef unsigned short u16;
typedef unsigned short u16x8 __attribute__((ext_vector_type(8)));
typedef unsigned short u16x4 __attribute__((ext_vector_type(4)));

#define EMBED 1024
#define HIDDEN 512
#define SEQ 4096
#define NBATCH 4
#define MTOT (NBATCH * SEQ)  // 16384

__device__ __forceinline__ u16 f32_to_bf16(float f) {
  union { float f; uint32_t u; } v; v.f = f;
  uint32_t r = v.u + 0x7fffu + ((v.u >> 16) & 1u);
  return (u16)(r >> 16);
}

// async global->LDS, 16B per lane; lds dst = wave-uniform base + lane*16
__device__ __forceinline__ void load_lds16(const u16* g, u16* l) {
  __builtin_amdgcn_global_load_lds(
      (const __attribute__((address_space(1))) void*)g,
      (__attribute__((address_space(3))) void*)l, 16, 0, 0);
}

// ---------- elementwise f32 -> bf16 ----------
__global__ __launch_bounds__(256) void cvt_bf16_kernel(const float* __restrict__ src,
                                                       u16* __restrict__ dst) {
  int i = blockIdx.x * 256 + threadIdx.x;
  float4 v = ((const float4*)src)[i];
  u16x4 o;
  o[0] = f32_to_bf16(v.x); o[1] = f32_to_bf16(v.y);
  o[2] = f32_to_bf16(v.z); o[3] = f32_to_bf16(v.w);
  ((u16x4*)dst)[i] = o;
}

// ---------- weight transpose+convert: src[K][N] f32 -> dst[N][K] bf16 ----------
__global__ __launch_bounds__(256) void transpose_w_kernel(const float* __restrict__ src,
                                                          u16* __restrict__ dst,
                                                          int log2N, int K) {
  int idx = blockIdx.x * 256 + threadIdx.x;
  int N = 1 << log2N;
  int k = idx >> log2N;
  int n = idx & (N - 1);
  dst[(size_t)n * K + k] = f32_to_bf16(src[idx]);
}

// ---------- GEMM: C[M,N] = A[M,K] * Bt[N,K]^T  (bf16 in, fp32 acc) ----------
// MODE 0: bf16 out * scale
// MODE 1: bf16 out, + bias[col] + resid[row*ldc+col]
// MODE 2: fp32 out
// MODE 3: bf16 out TRANSPOSED per batch: Vt[(batch*512+col)*4096 + (row&4095)]
template <int MODE>
__global__ __launch_bounds__(256, 3) void gemm_bt_kernel(
    const u16* __restrict__ A, const u16* __restrict__ Bt, void* __restrict__ Cout,
    const float* __restrict__ bias, const float* __restrict__ resid,
    int ldc, int K, float scale) {
  __shared__ u16 As[128][40];  // stride 40 u16 = 80B: 16B-aligned rows
  __shared__ u16 Bs[128][40];
  const int tid = threadIdx.x;
  const int lane = tid & 63;
  const int wave = tid >> 6;
  const int quad = lane >> 4;
  const int l15 = lane & 15;
  const int m0 = blockIdx.x * 128;
  const int n0 = blockIdx.y * 128;
  const int wm = (wave & 1) * 64;
  const int wn = (wave >> 1) * 64;

  f32x4 acc[4][4];
#pragma unroll
  for (int i = 0; i < 4; ++i)
#pragma unroll
    for (int j = 0; j < 4; ++j) {
      acc[i][j][0] = 0.f; acc[i][j][1] = 0.f; acc[i][j][2] = 0.f; acc[i][j][3] = 0.f;
    }

  for (int k0 = 0; k0 < K; k0 += 32) {
    __syncthreads();
#pragma unroll
    for (int p = 0; p < 2; ++p) {
      int c = tid + p * 256;        // 512 chunks of 8 elems: 128 rows x 4 chunks
      int r = c >> 2;
      int c8 = (c & 3) * 8;
      *(u16x8*)&As[r][c8] = *(const u16x8*)&A[(size_t)(m0 + r) * K + k0 + c8];
      *(u16x8*)&Bs[r][c8] = *(const u16x8*)&Bt[(size_t)(n0 + r) * K + k0 + c8];
    }
    __syncthreads();
    bf16x8 af[4], bfr[4];
#pragma unroll
    for (int i = 0; i < 4; ++i) af[i] = *(const bf16x8*)&As[wm + i * 16 + l15][quad * 8];
#pragma unroll
    for (int j = 0; j < 4; ++j) bfr[j] = *(const bf16x8*)&Bs[wn + j * 16 + l15][quad * 8];
#pragma unroll
    for (int i = 0; i < 4; ++i)
#pragma unroll
      for (int j = 0; j < 4; ++j)
        acc[i][j] = __builtin_amdgcn_mfma_f32_16x16x32_bf16(af[i], bfr[j], acc[i][j], 0, 0, 0);
  }

  // epilogue: C/D layout col=lane&15, row=quad*4+reg  [guide m89/m91]
#pragma unroll
  for (int i = 0; i < 4; ++i) {
    const int row = m0 + wm + i * 16 + quad * 4;
#pragma unroll
    for (int j = 0; j < 4; ++j) {
      const int col = n0 + wn + j * 16 + l15;
#pragma unroll
      for (int r = 0; r < 4; ++r) {
        float v = acc[i][j][r];
        const int rr = row + r;
        if (MODE == 0) {
          ((u16*)Cout)[(size_t)rr * ldc + col] = f32_to_bf16(v * scale);
        } else if (MODE == 1) {
          const size_t off = (size_t)rr * ldc + col;
          v += bias[col] + resid[off];
          ((u16*)Cout)[off] = f32_to_bf16(v);
        } else if (MODE == 2) {
          ((float*)Cout)[(size_t)rr * ldc + col] = v;
        } else {
          // transposed V store
          ((u16*)Cout)[((size_t)((rr >> 12) * 512 + col) << 12) + (rr & 4095)] = f32_to_bf16(v);
        }
      }
    }
  }
}

// ---------- flash attention ----------
// QKV: [16384, 1024] bf16 rows (Q|K), Q pre-scaled by 1/sqrt(512).
// VtG: [4][512][4096] bf16 (V transposed per batch).
// grid (SEQ/64, NBATCH); block 256 = 4 waves; wave handles 16 q-rows, full D=512.
__global__ __launch_bounds__(256, 1) void flash_kernel(const u16* __restrict__ QKV,
                                                       const u16* __restrict__ VtG,
                                                       u16* __restrict__ ctx) {
  __shared__ u16 Ks[32][520];      // K tile [kv][d], pad 512+8 (pad BETWEEN rows ok for lds-dma)
  __shared__ u16 Vs[512][32];      // V^T tile [d][kv], UNPADDED (64B rows, lds-dma contiguous)
  __shared__ u16 Ps[4][16][40];    // per-wave P round-trip [qrow][kv]
  const int tid = threadIdx.x;
  const int lane = tid & 63;
  const int wave = tid >> 6;
  const int quad = lane >> 4;
  const int l15 = lane & 15;
  const int base = blockIdx.y * SEQ;
  const int b512 = blockIdx.y * 512;
  const int q0 = blockIdx.x * 64;

  // Q fragments resident in registers: A-layout m=lane&15, k=quad*8+j  [guide m120]
  bf16x8 qf[16];
  {
    const u16* qp = QKV + (size_t)(base + q0 + wave * 16 + l15) * 1024 + quad * 8;
#pragma unroll
    for (int ks = 0; ks < 16; ++ks) qf[ks] = *(const bf16x8*)(qp + ks * 32);
  }

  f32x4 O[32];
#pragma unroll
  for (int i = 0; i < 32; ++i) { O[i][0] = 0.f; O[i][1] = 0.f; O[i][2] = 0.f; O[i][3] = 0.f; }
  float m_run[4] = {-INFINITY, -INFINITY, -INFINITY, -INFINITY};
  float l_run[4] = {0.f, 0.f, 0.f, 0.f};

  for (int kv0 = 0; kv0 < SEQ; kv0 += 32) {
    __syncthreads();
    // stage K tile (32x512) + V^T tile (512x32) via async global->LDS, 16B/lane
    {
      const int rk = wave * 8;
      const u16* kp = QKV + (size_t)(base + kv0 + rk) * 1024 + 512 + lane * 8;
      const u16* vp = VtG + (size_t)(b512 + wave * 128 + (lane >> 2)) * 4096 + kv0 + (lane & 3) * 8;
#pragma unroll
      for (int p = 0; p < 8; ++p) {
        load_lds16(kp + (size_t)p * 1024, &Ks[rk + p][0]);
        load_lds16(vp + (size_t)(p * 16) * 4096, &Vs[wave * 128 + p * 16][0]);
      }
    }
    __syncthreads();

    // S tile: 16 q-rows x 32 kv-cols (two 16x16 MFMA col-tiles)
    f32x4 s0, s1;
    s0[0] = 0.f; s0[1] = 0.f; s0[2] = 0.f; s0[3] = 0.f;
    s1[0] = 0.f; s1[1] = 0.f; s1[2] = 0.f; s1[3] = 0.f;
#pragma unroll
    for (int ks = 0; ks < 16; ++ks) {
      bf16x8 b0 = *(const bf16x8*)&Ks[l15][ks * 32 + quad * 8];
      bf16x8 b1 = *(const bf16x8*)&Ks[16 + l15][ks * 32 + quad * 8];
      s0 = __builtin_amdgcn_mfma_f32_16x16x32_bf16(qf[ks], b0, s0, 0, 0, 0);
      s1 = __builtin_amdgcn_mfma_f32_16x16x32_bf16(qf[ks], b1, s1, 0, 0, 0);
    }

    // online softmax; row = quad*4+reg lives in the 16 lanes of this quad
    float tmax[4], alpha[4], p0[4], p1[4], tsum[4];
#pragma unroll
    for (int r = 0; r < 4; ++r) tmax[r] = fmaxf(s0[r], s1[r]);
#pragma unroll
    for (int m = 1; m <= 8; m <<= 1)
#pragma unroll
      for (int r = 0; r < 4; ++r) tmax[r] = fmaxf(tmax[r], __shfl_xor(tmax[r], m));
    bool aone = true;
#pragma unroll
    for (int r = 0; r < 4; ++r) {
      float mnew = fmaxf(m_run[r], tmax[r]);
      alpha[r] = __expf(m_run[r] - mnew);
      m_run[r] = mnew;
      p0[r] = __expf(s0[r] - mnew);
      p1[r] = __expf(s1[r] - mnew);
      tsum[r] = p0[r] + p1[r];
      aone = aone && (alpha[r] == 1.0f);
    }
#pragma unroll
    for (int m = 1; m <= 8; m <<= 1)
#pragma unroll
      for (int r = 0; r < 4; ++r) tsum[r] += __shfl_xor(tsum[r], m);
#pragma unroll
    for (int r = 0; r < 4; ++r) l_run[r] = l_run[r] * alpha[r] + tsum[r];
    if (!__all(aone)) {
#pragma unroll
      for (int i = 0; i < 32; ++i)
#pragma unroll
        for (int r = 0; r < 4; ++r) O[i][r] *= alpha[r];
    }

    // P: C-layout -> LDS -> A-layout (wave-private: waitcnt, no barrier)
#pragma unroll
    for (int r = 0; r < 4; ++r) {
      Ps[wave][quad * 4 + r][l15] = f32_to_bf16(p0[r]);
      Ps[wave][quad * 4 + r][16 + l15] = f32_to_bf16(p1[r]);
    }
    asm volatile("s_waitcnt lgkmcnt(0)" ::: "memory");
    bf16x8 pf = *(const bf16x8*)&Ps[wave][l15][quad * 8];
#pragma unroll
    for (int nt = 0; nt < 32; ++nt) {
      bf16x8 vf = *(const bf16x8*)&Vs[nt * 16 + l15][quad * 8];
      O[nt] = __builtin_amdgcn_mfma_f32_16x16x32_bf16(pf, vf, O[nt], 0, 0, 0);
    }
  }

#pragma unroll
  for (int r = 0; r < 4; ++r) l_run[r] = 1.0f / l_run[r];
  const int orow = base + q0 + wave * 16 + quad * 4;
#pragma unroll
  for (int nt = 0; nt < 32; ++nt)
#pragma unroll
    for (int r = 0; r < 4; ++r)
      ctx[(size_t)(orow + r) * HIDDEN + nt * 16 + l15] = f32_to_bf16(O[nt][r] * l_run[r]);
}

// ---------- layernorm (in-place on d_out fp32, 1024 cols/row) ----------
__global__ __launch_bounds__(256) void ln_kernel(float* __restrict__ io,
                                                 const float* __restrict__ g,
                                                 const float* __restrict__ b) {
  const int row = blockIdx.x;
  const int tid = threadIdx.x;
  float* x = io + (size_t)row * EMBED;
  float4 v = *(const float4*)(x + tid * 4);
  float s1 = v.x + v.y + v.z + v.w;
  float s2 = v.x * v.x + v.y * v.y + v.z * v.z + v.w * v.w;
#pragma unroll
  for (int m = 1; m <= 32; m <<= 1) {
    s1 += __shfl_xor(s1, m);
    s2 += __shfl_xor(s2, m);
  }
  __shared__ float rs1[4], rs2[4];
  const int wave = tid >> 6;
  if ((tid & 63) == 0) { rs1[wave] = s1; rs2[wave] = s2; }
  __syncthreads();
  s1 = rs1[0] + rs1[1] + rs1[2] + rs1[3];
  s2 = rs2[0] + rs2[1] + rs2[2] + rs2[3];
  const float mu = s1 * (1.f / EMBED);
  const float var = s2 * (1.f / EMBED) - mu * mu;
  const float rinv = rsqrtf(var + 1e-5f);
  float4 gg = *(const float4*)(g + tid * 4);
  float4 bb = *(const float4*)(b + tid * 4);
  float4 o;
  o.x = (v.x - mu) * rinv * gg.x + bb.x;
  o.y = (v.y - mu) * rinv * gg.y + bb.y;
  o.z = (v.z - mu) * rinv * gg.z + bb.z;
  o.w = (v.w - mu) * rinv * gg.w + bb.w;
  *(float4*)(x + tid * 4) = o;
}

// ---------- launch ----------
extern "C" void kernel_launch(void* const* d_in, const int* in_sizes, int n_in,
                              void* d_out, int out_size, void* d_ws, size_t ws_size,
                              hipStream_t stream) {
  const float* q_feat = (const float*)d_in[0];
  const float* kv_feat = (const float*)d_in[1];
  const float* Wq = (const float*)d_in[2];
  const float* Wk = (const float*)d_in[3];
  const float* Wv = (const float*)d_in[4];
  const float* Wo = (const float*)d_in[5];
  const float* bo = (const float*)d_in[6];
  const float* Wfc = (const float*)d_in[7];
  const float* ln_g = (const float*)d_in[8];
  const float* ln_b = (const float*)d_in[9];
  float* out = (float*)d_out;

  // ws carve (total 140,509,184 B)
  char* ws = (char*)d_ws;
  u16* Aq    = (u16*)(ws + 0);           // 33,554,432  (later aliased as out1)
  u16* Akv   = (u16*)(ws + 33554432);    // 33,554,432
  u16* Wcat  = (u16*)(ws + 67108864);    //  3,145,728  [1536,1024] bf16 (Wq^T|Wk^T|Wv^T)
  u16* Wo_t  = (u16*)(ws + 70254592);    //  1,048,576  [1024,512]
  u16* Wfc_t = (u16*)(ws + 71303168);    //  2,097,152  [1024,1024]
  u16* QKV   = (u16*)(ws + 73400320);    // 33,554,432  [16384,1024] (Q|K)
  u16* Vt    = (u16*)(ws + 106954752);   // 16,777,216  [4][512][4096]
  u16* ctx   = (u16*)(ws + 123731968);   // 16,777,216  [16384,512]
  u16* out1  = Aq;                       // alias: Aq dead after Q-projection

  const float qscale = 0.044194173824159216f;  // 1/sqrt(512)

  // 1. activations -> bf16
  cvt_bf16_kernel<<<MTOT * EMBED / 1024, 256, 0, stream>>>(q_feat, Aq);
  cvt_bf16_kernel<<<MTOT * EMBED / 1024, 256, 0, stream>>>(kv_feat, Akv);
  // 2. weights -> transposed bf16
  transpose_w_kernel<<<(EMBED * HIDDEN) / 256, 256, 0, stream>>>(Wq, Wcat, 9, EMBED);
  transpose_w_kernel<<<(EMBED * HIDDEN) / 256, 256, 0, stream>>>(Wk, Wcat + 512 * 1024, 9, EMBED);
  transpose_w_kernel<<<(EMBED * HIDDEN) / 256, 256, 0, stream>>>(Wv, Wcat + 1024 * 1024, 9, EMBED);
  transpose_w_kernel<<<(HIDDEN * EMBED) / 256, 256, 0, stream>>>(Wo, Wo_t, 10, HIDDEN);
  transpose_w_kernel<<<(EMBED * EMBED) / 256, 256, 0, stream>>>(Wfc, Wfc_t, 10, EMBED);
  // 3a. Q projection from q_feat (pre-scaled): QKV cols [0,512)
  gemm_bt_kernel<0><<<dim3(MTOT / 128, 4), 256, 0, stream>>>(
      Aq, Wcat, QKV, nullptr, nullptr, 1024, EMBED, qscale);
  // 3b. K projection from kv_feat: QKV cols [512,1024)
  gemm_bt_kernel<0><<<dim3(MTOT / 128, 4), 256, 0, stream>>>(
      Akv, Wcat + 512 * 1024, QKV + 512, nullptr, nullptr, 1024, EMBED, 1.0f);
  // 3c. V projection from kv_feat -> transposed Vt [4][512][4096]
  gemm_bt_kernel<3><<<dim3(MTOT / 128, 4), 256, 0, stream>>>(
      Akv, Wcat + 1024 * 1024, Vt, nullptr, nullptr, 0, EMBED, 1.0f);
  // 4. flash attention
  flash_kernel<<<dim3(SEQ / 64, NBATCH), 256, 0, stream>>>(QKV, Vt, ctx);
  // 5. out1 = ctx @ Wo^T + bo + q_feat  (bf16)
  gemm_bt_kernel<1><<<dim3(MTOT / 128, EMBED / 128), 256, 0, stream>>>(
      ctx, Wo_t, out1, bo, q_feat, EMBED, HIDDEN, 0.f);
  // 6. out2 = out1 @ Wfc^T (fp32 -> d_out)
  gemm_bt_kernel<2><<<dim3(MTOT / 128, EMBED / 128), 256, 0, stream>>>(
      out1, Wfc_t, out, nullptr, nullptr, EMBED, EMBED, 0.f);
  // 7. layernorm in-place
  ln_kernel<<<MTOT, 256, 0, stream>>>(out, ln_g, ln_b);

  (void)in_sizes; (void)n_in; (void)out_size; (void)ws_size;
}